// Round 1
// baseline (192.403 us; speedup 1.0000x reference)
//
#include <hip/hip_runtime.h>
#include <math.h>

#define HIDN 128
#define NPTS 32768
#define PTS_PER_BLK 16
#define NBLK (NPTS / PTS_PER_BLK)   // 2048

// Lame coefficients: nu=0.49, nu_denom = max(1-0.98,1e-5)=0.02
#define MU_COEF 0.33557046979865773f
#define LM_COEF 16.442953020134228f

typedef float f32x4  __attribute__((ext_vector_type(4)));
typedef short bf16x8 __attribute__((ext_vector_type(8)));

__device__ __forceinline__ unsigned short f2bf(float f) {
    unsigned u = __builtin_bit_cast(unsigned, f);
    u += 0x7fffu + ((u >> 16) & 1u);          // RNE
    return (unsigned short)(u >> 16);
}

// packed bf16 convert (RNE), 2 values per instruction
__device__ __forceinline__ unsigned cvtpk2(float lo, float hi) {
    unsigned r;
    asm("v_cvt_pk_bf16_f32 %0, %1, %2" : "=v"(r) : "v"(lo), "v"(hi));
    return r;
}

__device__ __forceinline__ float tanh_fast(float x) {
    // tanh(x) = 1 - 2/(e^{2x}+1);  v_exp_f32 computes 2^x
    float e = __builtin_amdgcn_exp2f(x * 2.885390081777927f); // 2*log2(e)
    return 1.0f - 2.0f * __builtin_amdgcn_rcpf(e + 1.0f);
}

// ws layout (floats):
//   [0..7]     loss accumulators: 0 bce, 1 sq, 2 phys, 3 el
//   [64..]     mtab: 128 x 8 f32 {wd0,wd1,wd2,wp,wsv,b2,0,0}
//   [2048..]   W2bf: 128x128 bf16 (ushort), m-major: W2bf[m*128+h] = bf16(W2[h,m])
__global__ void prep_kernel(const float* __restrict__ W2,
                            const float* __restrict__ Wd,
                            const float* __restrict__ Wp,
                            const float* __restrict__ Wsv,
                            const float* __restrict__ b2,
                            float* __restrict__ ws)
{
    int tid = blockIdx.x * blockDim.x + threadIdx.x;
    if (tid < 8) ws[tid] = 0.0f;
    if (tid < HIDN) {
        float* mt = ws + 64 + tid * 8;
        mt[0] = Wd[tid * 3 + 0]; mt[1] = Wd[tid * 3 + 1]; mt[2] = Wd[tid * 3 + 2];
        mt[3] = Wp[tid]; mt[4] = Wsv[tid]; mt[5] = b2[tid];
        mt[6] = 0.0f; mt[7] = 0.0f;
    }
    unsigned short* W2bf = (unsigned short*)(ws + 2048);
    for (int i = tid; i < HIDN * HIDN; i += gridDim.x * blockDim.x) {
        int h = i >> 7, m = i & 127;          // coalesced read W2[i], scattered 2B store
        W2bf[m * HIDN + h] = f2bf(W2[i]);
    }
}

// LDS: A — 10 channels x 16 pts x 128 bf16, XOR-swizzled chunks   = 40960 B
//      red2 — 64 rows x 8 f32 (disjoint, no extra barrier needed) =  2048 B
__global__ __launch_bounds__(256, 3) void pinn_main(
    const float* __restrict__ coords,
    const float* __restrict__ labels,
    const float* __restrict__ tstiff,
    const float* __restrict__ W1,
    const float* __restrict__ b1,
    const float* __restrict__ bp,
    const float* __restrict__ bs,
    const float* __restrict__ ws_ro,
    float* __restrict__ accum)
{
    const float* mtab = ws_ro + 64;
    const unsigned short* W2bf = (const unsigned short*)(ws_ro + 2048);

    __shared__ __align__(16) char smem[43008];
    float* red2 = (float*)(smem + 40960);

    const int tid  = threadIdx.x;
    const int wave = __builtin_amdgcn_readfirstlane(tid >> 6);
    const int lane = tid & 63;
    const int blk  = blockIdx.x;

    // ---------- phase 1: build the 10 bf16 A-channels for 16 points ----------
    // thread (b = tid>>4, hc = tid&15): point b, h-range [hc*8, hc*8+8)
    // -> lanes sweep h => coalesced W1/b1 float4 loads, conflict-free LDS row writes
    {
        const int b  = tid >> 4;
        const int hc = tid & 15;
        const int h0 = hc * 8;
        const int gb = blk * PTS_PER_BLK + b;
        const float x0 = coords[gb * 3 + 0];
        const float x1 = coords[gb * 3 + 1];
        const float x2 = coords[gb * 3 + 2];
        const f32x4 w0lo = *(const f32x4*)(W1 + h0);
        const f32x4 w0hi = *(const f32x4*)(W1 + h0 + 4);
        const f32x4 w1lo = *(const f32x4*)(W1 + HIDN + h0);
        const f32x4 w1hi = *(const f32x4*)(W1 + HIDN + h0 + 4);
        const f32x4 w2lo = *(const f32x4*)(W1 + 2 * HIDN + h0);
        const f32x4 w2hi = *(const f32x4*)(W1 + 2 * HIDN + h0 + 4);
        const f32x4 blo  = *(const f32x4*)(b1 + h0);
        const f32x4 bhi  = *(const f32x4*)(b1 + h0 + 4);

        unsigned pk[10][4];
#pragma unroll
        for (int p = 0; p < 4; ++p) {
            float ca[2][10];
#pragma unroll
            for (int s = 0; s < 2; ++s) {
                const int i = 2 * p + s;
                const float wa = (i < 4) ? w0lo[i & 3] : w0hi[i & 3];
                const float wb = (i < 4) ? w1lo[i & 3] : w1hi[i & 3];
                const float wc = (i < 4) ? w2lo[i & 3] : w2hi[i & 3];
                const float bb = (i < 4) ? blo[i & 3]  : bhi[i & 3];
                const float z  = fmaf(x0, wa, fmaf(x1, wb, fmaf(x2, wc, bb)));
                const float a  = tanh_fast(z);
                const float g  = fmaf(-a, a, 1.0f);
                const float ag = a * g;
                const float p0 = ag * wa, p1 = ag * wb, p2 = ag * wc;
                ca[s][0] = a;
                ca[s][1] = g * wa; ca[s][2] = g * wb; ca[s][3] = g * wc;
                ca[s][4] = p0 * wa; ca[s][5] = p0 * wb; ca[s][6] = p0 * wc;
                ca[s][7] = p1 * wb; ca[s][8] = p1 * wc; ca[s][9] = p2 * wc;
            }
#pragma unroll
            for (int ch = 0; ch < 10; ++ch)
                pk[ch][p] = cvtpk2(ca[0][ch], ca[1][ch]);
        }
        // XOR-swizzled 16B chunk within the 256B row (write side)
        const int sw = (h0 * 2) ^ ((b & 7) << 4);
#pragma unroll
        for (int ch = 0; ch < 10; ++ch) {
            *(uint4*)(smem + ch * 4096 + b * 256 + sw) =
                make_uint4(pk[ch][0], pk[ch][1], pk[ch][2], pk[ch][3]);
        }
    }
    __syncthreads();

    // ---------- phase 2: GEMM, operands SWAPPED: D[row=m][col=point] ----------
    const int l = lane & 15;      // A row (m within 16-tile) / B col (point)
    const int q = lane >> 4;      // quad: k = q*8 + j
    const int lsw = (l & 7) << 4; // read-side swizzle

    f32x4 acc[10][2] = {};
#pragma unroll
    for (int ks = 0; ks < 4; ++ks) {
        const int hk = ks * 32 + q * 8;
        bf16x8 bfr0 = *(const bf16x8*)(W2bf + (wave * 32 + l) * HIDN + hk);
        bf16x8 bfr1 = *(const bf16x8*)(W2bf + (wave * 32 + 16 + l) * HIDN + hk);
        const int coff = (ks * 64 + q * 16) ^ lsw;
#pragma unroll
        for (int ch = 0; ch < 10; ++ch) {
            bf16x8 afr = *(const bf16x8*)(smem + ch * 4096 + l * 256 + coff);
            acc[ch][0] = __builtin_amdgcn_mfma_f32_16x16x32_bf16(bfr0, afr, acc[ch][0], 0, 0, 0);
            acc[ch][1] = __builtin_amdgcn_mfma_f32_16x16x32_bf16(bfr1, afr, acc[ch][1], 0, 0, 0);
        }
    }

    // ---------- phase 3: epilogue; lane holds point=l, m = wave*32+mt*16+q*4+r ----------
    float sum[8] = {0, 0, 0, 0, 0, 0, 0, 0};   // zp, zs, lap0..2, gd0..2
#pragma unroll
    for (int mt = 0; mt < 2; ++mt) {
#pragma unroll
        for (int r = 0; r < 4; ++r) {
            const int m = wave * 32 + mt * 16 + q * 4 + r;
            const f32x4 mw0 = *(const f32x4*)(mtab + m * 8);
            const f32x4 mw1 = *(const f32x4*)(mtab + m * 8 + 4);
            const float wd0 = mw0[0], wd1 = mw0[1], wd2 = mw0[2], wpv = mw0[3];
            const float wsv = mw1[0], b2v = mw1[1];
            const float z2 = acc[0][mt][r] + b2v;
            const float a2 = tanh_fast(z2);
            const float g2 = fmaf(-a2, a2, 1.0f);
            const float d2 = -2.0f * a2 * g2;
            const float t0 = acc[1][mt][r], t1 = acc[2][mt][r], t2 = acc[3][mt][r];
            const float q00 = acc[4][mt][r], q01 = acc[5][mt][r], q02 = acc[6][mt][r];
            const float q11 = acc[7][mt][r], q12 = acc[8][mt][r], q22 = acc[9][mt][r];
            const float qtr = q00 + q11 + q22;
            const float tt  = t0 * t0 + t1 * t1 + t2 * t2;
            const float m2g2 = -2.0f * g2;
            const float Lm  = fmaf(m2g2, qtr, d2 * tt);
            const float wt  = wd0 * t0 + wd1 * t1 + wd2 * t2;
            const float dwt = d2 * wt;
            const float r0 = wd0 * q00 + wd1 * q01 + wd2 * q02;
            const float r1 = wd0 * q01 + wd1 * q11 + wd2 * q12;
            const float r2 = wd0 * q02 + wd1 * q12 + wd2 * q22;
            sum[0] = fmaf(wpv, a2, sum[0]);
            sum[1] = fmaf(wsv, a2, sum[1]);
            sum[2] = fmaf(wd0, Lm, sum[2]);
            sum[3] = fmaf(wd1, Lm, sum[3]);
            sum[4] = fmaf(wd2, Lm, sum[4]);
            sum[5] += fmaf(m2g2, r0, dwt * t0);
            sum[6] += fmaf(m2g2, r1, dwt * t1);
            sum[7] += fmaf(m2g2, r2, dwt * t2);
        }
    }

    // ---------- phase 3.5: m-reduction = 2 shuffles (over quads) + 2KB exchange ----------
#pragma unroll
    for (int k = 0; k < 8; ++k) {
        sum[k] += __shfl_xor(sum[k], 16);
        sum[k] += __shfl_xor(sum[k], 32);
    }
    if (q == 0) {
        float4* dst = (float4*)(red2 + (wave * 16 + l) * 8);
        dst[0] = make_float4(sum[0], sum[1], sum[2], sum[3]);
        dst[1] = make_float4(sum[4], sum[5], sum[6], sum[7]);
    }
    __syncthreads();

    // ---------- phase 4: per-point finalize (16 threads) ----------
    if (tid < 16) {
        float v[8] = {0, 0, 0, 0, 0, 0, 0, 0};
#pragma unroll
        for (int w = 0; w < 4; ++w) {
            const float4* s = (const float4*)(red2 + (w * 16 + tid) * 8);
            const float4 pa = s[0], pb = s[1];
            v[0] += pa.x; v[1] += pa.y; v[2] += pa.z; v[3] += pa.w;
            v[4] += pb.x; v[5] += pb.y; v[6] += pb.z; v[7] += pb.w;
        }
        const int gb = blk * PTS_PER_BLK + tid;
        const float fzp = v[0] + bp[0];
        const float fzs = v[1] + bs[0];
        float pred = 1.0f / (1.0f + expf(-fzp));
        pred = fminf(fmaxf(pred, 1e-7f), 1.0f - 1e-7f);
        const float E = fmaxf(fzs, 0.0f) + log1pf(expf(-fabsf(fzs)));
        const float mu = E * MU_COEF;
        const float cc = E * LM_COEF + mu;
        const float rr0 = mu * v[2] + cc * v[5];
        const float rr1 = mu * v[3] + cc * v[6];
        const float rr2 = mu * v[4] + cc * v[7];
        float phys_t = rr0 * rr0 + rr1 * rr1 + rr2 * rr2;
        float tl = labels[gb];
        tl = fminf(fmaxf(tl, 0.0f), 1.0f);
        float bce_t = -(tl * logf(pred) + (1.0f - tl) * logf(1.0f - pred));
        const float dsv = E - tstiff[gb];
        float sq_t = dsv * dsv;
        float el_t = fmaxf(-E, 0.0f) + fmaxf(E - 15.0f, 0.0f);
#pragma unroll
        for (int mk = 1; mk < 16; mk <<= 1) {
            bce_t  += __shfl_xor(bce_t, mk);
            sq_t   += __shfl_xor(sq_t, mk);
            phys_t += __shfl_xor(phys_t, mk);
            el_t   += __shfl_xor(el_t, mk);
        }
        if (tid == 0) {
            atomicAdd(accum + 0, bce_t);
            atomicAdd(accum + 1, sq_t);
            atomicAdd(accum + 2, phys_t);
            atomicAdd(accum + 3, el_t);
        }
    }
}

__global__ void finalize_kernel(const float* __restrict__ accum,
                                float* __restrict__ out)
{
    if (threadIdx.x == 0 && blockIdx.x == 0) {
        const float invB = 1.0f / (float)NPTS;
        const float bce  = accum[0] * invB;
        const float data = bce + 0.5f * accum[1] * invB;
        const float phys = accum[2] * invB;
        const float el   = accum[3] * invB;
        out[0] = data + 0.1f * phys + 0.05f * el;
        out[1] = data;
        out[2] = phys;
        out[3] = el;
    }
}

extern "C" void kernel_launch(void* const* d_in, const int* in_sizes, int n_in,
                              void* d_out, int out_size, void* d_ws, size_t ws_size,
                              hipStream_t stream)
{
    const float* coords = (const float*)d_in[0];
    const float* labels = (const float*)d_in[1];
    const float* tstiff = (const float*)d_in[2];
    const float* W1  = (const float*)d_in[3];
    const float* b1  = (const float*)d_in[4];
    const float* W2  = (const float*)d_in[5];
    const float* b2  = (const float*)d_in[6];
    const float* Wp  = (const float*)d_in[7];
    const float* bp  = (const float*)d_in[8];
    const float* Wsv = (const float*)d_in[9];
    const float* bs  = (const float*)d_in[10];
    const float* Wd  = (const float*)d_in[11];
    // d_in[12] = bd : unused (constant offset has zero Hessian)

    float* ws  = (float*)d_ws;
    float* out = (float*)d_out;

    prep_kernel<<<64, 256, 0, stream>>>(W2, Wd, Wp, Wsv, b2, ws);
    pinn_main<<<NBLK, 256, 0, stream>>>(coords, labels, tstiff, W1, b1,
                                        bp, bs, ws, ws);
    finalize_kernel<<<1, 64, 0, stream>>>(ws, out);
}

// Round 4
// 117.891 us; speedup vs baseline: 1.6320x; 1.6320x over previous
//
#include <hip/hip_runtime.h>
#include <math.h>

#define HIDN 128
#define NPTS 32768
#define PTS_PER_BLK 16
#define NBLK (NPTS / PTS_PER_BLK)   // 2048

// Lame coefficients: nu=0.49, nu_denom = max(1-0.98,1e-5)=0.02
#define MU_COEF 0.33557046979865773f
#define LM_COEF 16.442953020134228f

typedef float f32x4  __attribute__((ext_vector_type(4)));
typedef short bf16x8 __attribute__((ext_vector_type(8)));

// ws layout (floats):
//   [0..7]     loss accumulators: 0 bce, 1 sq, 2 phys, 3 el
//   [128..]    tab: 128 x 12 f32 {w0,w1,w2,b1, p00,p01,p02,p11,p12,p22, 0,0}
//   [2048..]   W2bf: 128x128 bf16 (ushort), m-major: W2bf[m*128+h] = bf16(W2[h,m])

__device__ __forceinline__ unsigned short f2bf(float f) {
    unsigned u = __builtin_bit_cast(unsigned, f);
    u += 0x7fffu + ((u >> 16) & 1u);          // RNE
    return (unsigned short)(u >> 16);
}

// packed bf16 convert (RNE): low16 = bf16(lo), high16 = bf16(hi)
__device__ __forceinline__ unsigned cvtpk2(float lo, float hi) {
    unsigned r;
    asm("v_cvt_pk_bf16_f32 %0, %1, %2" : "=v"(r) : "v"(lo), "v"(hi));
    return r;
}

__device__ __forceinline__ float tanh_fast(float x) {
    // tanh(x) = 1 - 2/(e^{2x}+1);  v_exp_f32 computes 2^x
    float e = __builtin_amdgcn_exp2f(x * 2.885390081777927f); // 2*log2(e)
    return 1.0f - 2.0f * __builtin_amdgcn_rcpf(e + 1.0f);
}

__global__ void prep_kernel(const float* __restrict__ W1,
                            const float* __restrict__ b1,
                            const float* __restrict__ W2,
                            float* __restrict__ ws)
{
    float* accum = ws;
    float* tab   = ws + 128;
    unsigned short* W2bf = (unsigned short*)(ws + 2048);
    int tid = blockIdx.x * blockDim.x + threadIdx.x;
    if (tid < 8) accum[tid] = 0.0f;
    if (tid < HIDN) {
        float w0 = W1[0 * HIDN + tid];
        float w1 = W1[1 * HIDN + tid];
        float w2 = W1[2 * HIDN + tid];
        float* t = tab + tid * 12;
        t[0] = w0; t[1] = w1; t[2] = w2; t[3] = b1[tid];
        t[4] = w0 * w0; t[5] = w0 * w1; t[6] = w0 * w2;
        t[7] = w1 * w1; t[8] = w1 * w2; t[9] = w2 * w2;
        t[10] = 0.0f; t[11] = 0.0f;
    }
    for (int i = tid; i < HIDN * HIDN; i += gridDim.x * blockDim.x) {
        int m = i >> 7, h = i & 127;
        W2bf[m * HIDN + h] = f2bf(W2[h * HIDN + m]);
    }
}

// LDS: phase A — 10 channels x 16 pts x 136(bf16 padded)   = 43520 B
//      phase B — red[16 pts][64 slots][8 f32]              = 32768 B (aliases)
//      red2[4][4] at +43520
__global__ __launch_bounds__(256, 3) void pinn_main(
    const float* __restrict__ coords,
    const float* __restrict__ labels,
    const float* __restrict__ tstiff,
    const float* __restrict__ b2,
    const float* __restrict__ Wp, const float* __restrict__ bp,
    const float* __restrict__ Wsv, const float* __restrict__ bs,
    const float* __restrict__ Wd,
    const float* __restrict__ ws_ro,
    float* __restrict__ accum)
{
    const float* tab = ws_ro + 128;
    const unsigned short* W2bf = (const unsigned short*)(ws_ro + 2048);

    __shared__ __align__(16) char smem[43584];
    unsigned short* A  = (unsigned short*)smem;          // [ch][16][136]
    float*          red  = (float*)smem;                 // [16][64][8]
    float*          red2 = (float*)(smem + 43520);       // [4][4]

    const int tid  = threadIdx.x;
    const int wave = __builtin_amdgcn_readfirstlane(tid >> 6);
    const int lane = tid & 63;
    const int blk  = blockIdx.x;

    // ---------- phase 1: build the 10 bf16 A-channels for 16 points ----------
    {
        const int b  = tid & 15;
        const int hc = tid >> 4;            // 0..15 -> h block of 8
        const int h0 = hc * 8;
        const int gb = blk * PTS_PER_BLK + b;
        const float x0 = coords[gb * 3 + 0];
        const float x1 = coords[gb * 3 + 1];
        const float x2 = coords[gb * 3 + 2];
        unsigned pk[10][4];
#pragma unroll
        for (int p = 0; p < 4; ++p) {
            float ca[2][10];
#pragma unroll
            for (int s = 0; s < 2; ++s) {
                const int i = 2 * p + s;
                const float* t = tab + (h0 + i) * 12;
                float z = fmaf(x0, t[0], fmaf(x1, t[1], fmaf(x2, t[2], t[3])));
                float a  = tanh_fast(z);
                float g  = fmaf(-a, a, 1.0f);
                float ag = a * g;
                ca[s][0] = a;
                ca[s][1] = g * t[0]; ca[s][2] = g * t[1]; ca[s][3] = g * t[2];
                ca[s][4] = ag * t[4]; ca[s][5] = ag * t[5]; ca[s][6] = ag * t[6];
                ca[s][7] = ag * t[7]; ca[s][8] = ag * t[8]; ca[s][9] = ag * t[9];
            }
#pragma unroll
            for (int ch = 0; ch < 10; ++ch)
                pk[ch][p] = cvtpk2(ca[0][ch], ca[1][ch]);
        }
#pragma unroll
        for (int ch = 0; ch < 10; ++ch) {
            uint4* dst = (uint4*)(A + ch * (16 * 136) + b * 136 + h0);
            *dst = make_uint4(pk[ch][0], pk[ch][1], pk[ch][2], pk[ch][3]);
        }
    }
    __syncthreads();

    // ---------- phase 2: GEMM — wave owns m in [wave*32, wave*32+32) ----------
    const int l = lane & 15;      // A row (point) / B col (m) within tile
    const int q = lane >> 4;      // quad: k = q*8 + j

    f32x4 acc[10][2] = {};
#pragma unroll
    for (int ks = 0; ks < 4; ++ks) {
        const int hk = ks * 32 + q * 8;
        bf16x8 bfr[2];
#pragma unroll
        for (int mt = 0; mt < 2; ++mt) {
            const int m = wave * 32 + mt * 16 + l;
            bfr[mt] = *(const bf16x8*)(W2bf + m * HIDN + hk);
        }
#pragma unroll
        for (int ch = 0; ch < 10; ++ch) {
            bf16x8 afr = *(const bf16x8*)(A + ch * (16 * 136) + l * 136 + hk);
            acc[ch][0] = __builtin_amdgcn_mfma_f32_16x16x32_bf16(afr, bfr[0], acc[ch][0], 0, 0, 0);
            acc[ch][1] = __builtin_amdgcn_mfma_f32_16x16x32_bf16(afr, bfr[1], acc[ch][1], 0, 0, 0);
        }
    }

    // ---------- phase 3: epilogue per (b,m), accumulate over this wave's m ----------
    float sum[4][8] = {};   // [r][k]: zp, zs, lap0..2, gd0..2
#pragma unroll
    for (int mt = 0; mt < 2; ++mt) {
        const int m = wave * 32 + mt * 16 + l;
        const float wd0 = Wd[m * 3 + 0];
        const float wd1 = Wd[m * 3 + 1];
        const float wd2 = Wd[m * 3 + 2];
        const float wp  = Wp[m];
        const float wsv = Wsv[m];
        const float b2v = b2[m];
#pragma unroll
        for (int r = 0; r < 4; ++r) {
            const float z2 = acc[0][mt][r] + b2v;
            const float a2 = tanh_fast(z2);
            const float g2 = fmaf(-a2, a2, 1.0f);
            const float d2 = -2.0f * a2 * g2;
            const float t0 = acc[1][mt][r], t1 = acc[2][mt][r], t2 = acc[3][mt][r];
            const float q00 = acc[4][mt][r], q01 = acc[5][mt][r], q02 = acc[6][mt][r];
            const float q11 = acc[7][mt][r], q12 = acc[8][mt][r], q22 = acc[9][mt][r];
            const float qtr = q00 + q11 + q22;
            const float tt  = t0 * t0 + t1 * t1 + t2 * t2;
            const float Lm  = fmaf(-2.0f * g2, qtr, d2 * tt);  // g2*tr(Q)+d2*|t|^2, Q=-2q
            const float wt  = wd0 * t0 + wd1 * t1 + wd2 * t2;
            const float m2g2 = -2.0f * g2;
            const float dwt  = d2 * wt;
            const float r0 = wd0 * q00 + wd1 * q01 + wd2 * q02;
            const float r1 = wd0 * q01 + wd1 * q11 + wd2 * q12;
            const float r2 = wd0 * q02 + wd1 * q12 + wd2 * q22;
            sum[r][0] += wp  * a2;
            sum[r][1] += wsv * a2;
            sum[r][2] += wd0 * Lm;
            sum[r][3] += wd1 * Lm;
            sum[r][4] += wd2 * Lm;
            sum[r][5] += m2g2 * r0 + dwt * t0;
            sum[r][6] += m2g2 * r1 + dwt * t1;
            sum[r][7] += m2g2 * r2 + dwt * t2;
        }
    }
    __syncthreads();   // done reading A; red aliases it

#pragma unroll
    for (int r = 0; r < 4; ++r) {
        const int b = q * 4 + r;
        const int slot = wave * 16 + l;
        float4* dst = (float4*)(red + (b * 64 + slot) * 8);
        dst[0] = make_float4(sum[r][0], sum[r][1], sum[r][2], sum[r][3]);
        dst[1] = make_float4(sum[r][4], sum[r][5], sum[r][6], sum[r][7]);
    }
    __syncthreads();

    // ---------- phase 4: per-point finalize ----------
    {
        const int b  = tid >> 4;    // 0..15
        const int l2 = tid & 15;
        float v[8] = {};
#pragma unroll
        for (int w = 0; w < 4; ++w) {
            const float4* src = (const float4*)(red + (b * 64 + w * 16 + l2) * 8);
            float4 p0 = src[0], p1 = src[1];
            v[0] += p0.x; v[1] += p0.y; v[2] += p0.z; v[3] += p0.w;
            v[4] += p1.x; v[5] += p1.y; v[6] += p1.z; v[7] += p1.w;
        }
#pragma unroll
        for (int k = 0; k < 8; ++k) {
            v[k] += __shfl_xor(v[k], 1);
            v[k] += __shfl_xor(v[k], 2);
            v[k] += __shfl_xor(v[k], 4);
            v[k] += __shfl_xor(v[k], 8);
        }
        float bce_t = 0.f, sq_t = 0.f, phys_t = 0.f, el_t = 0.f;
        if (l2 == 0) {
            const int gb = blk * PTS_PER_BLK + b;
            const float fzp = v[0] + bp[0];
            const float fzs = v[1] + bs[0];
            float pred = 1.0f / (1.0f + expf(-fzp));
            pred = fminf(fmaxf(pred, 1e-7f), 1.0f - 1e-7f);
            const float E = fmaxf(fzs, 0.0f) + log1pf(expf(-fabsf(fzs)));
            const float mu = E * MU_COEF;
            const float cc = E * LM_COEF + mu;
            const float rr0 = mu * v[2] + cc * v[5];
            const float rr1 = mu * v[3] + cc * v[6];
            const float rr2 = mu * v[4] + cc * v[7];
            phys_t = rr0 * rr0 + rr1 * rr1 + rr2 * rr2;
            float tl = labels[gb];
            tl = fminf(fmaxf(tl, 0.0f), 1.0f);
            bce_t = -(tl * logf(pred) + (1.0f - tl) * logf(1.0f - pred));
            const float dsv = E - tstiff[gb];
            sq_t = dsv * dsv;
            el_t = fmaxf(-E, 0.0f) + fmaxf(E - 15.0f, 0.0f);
        }
#pragma unroll
        for (int m = 16; m < 64; m <<= 1) {
            bce_t  += __shfl_xor(bce_t, m);
            sq_t   += __shfl_xor(sq_t, m);
            phys_t += __shfl_xor(phys_t, m);
            el_t   += __shfl_xor(el_t, m);
        }
        if (lane == 0) {
            red2[wave * 4 + 0] = bce_t;
            red2[wave * 4 + 1] = sq_t;
            red2[wave * 4 + 2] = phys_t;
            red2[wave * 4 + 3] = el_t;
        }
    }
    __syncthreads();
    if (tid < 4) {
        float s = red2[0 * 4 + tid] + red2[1 * 4 + tid] + red2[2 * 4 + tid] + red2[3 * 4 + tid];
        atomicAdd(accum + tid, s);
    }
}

__global__ void finalize_kernel(const float* __restrict__ accum,
                                float* __restrict__ out)
{
    if (threadIdx.x == 0 && blockIdx.x == 0) {
        const float invB = 1.0f / (float)NPTS;
        const float bce  = accum[0] * invB;
        const float data = bce + 0.5f * accum[1] * invB;
        const float phys = accum[2] * invB;
        const float el   = accum[3] * invB;
        out[0] = data + 0.1f * phys + 0.05f * el;
        out[1] = data;
        out[2] = phys;
        out[3] = el;
    }
}

extern "C" void kernel_launch(void* const* d_in, const int* in_sizes, int n_in,
                              void* d_out, int out_size, void* d_ws, size_t ws_size,
                              hipStream_t stream)
{
    const float* coords = (const float*)d_in[0];
    const float* labels = (const float*)d_in[1];
    const float* tstiff = (const float*)d_in[2];
    const float* W1  = (const float*)d_in[3];
    const float* b1  = (const float*)d_in[4];
    const float* W2  = (const float*)d_in[5];
    const float* b2  = (const float*)d_in[6];
    const float* Wp  = (const float*)d_in[7];
    const float* bp  = (const float*)d_in[8];
    const float* Wsv = (const float*)d_in[9];
    const float* bs  = (const float*)d_in[10];
    const float* Wd  = (const float*)d_in[11];
    // d_in[12] = bd : unused (constant offset has zero Hessian)

    float* ws  = (float*)d_ws;
    float* out = (float*)d_out;

    prep_kernel<<<64, 256, 0, stream>>>(W1, b1, W2, ws);
    pinn_main<<<NBLK, 256, 0, stream>>>(coords, labels, tstiff, b2,
                                        Wp, bp, Wsv, bs, Wd, ws, ws);
    finalize_kernel<<<1, 64, 0, stream>>>(ws, out);
}